// Round 9
// baseline (128.765 us; speedup 1.0000x reference)
//
#include <hip/hip_runtime.h>

// DynamicGaussianBlur: [B=4, D=160, H=160, W=160, C=2] fp32, sigma [4,3],
// separable 3D gaussian, window 13 (radius 6), SAME zero padding.
// Axis convs commute; reordered so COLD reads are contiguous:
//   1: fused H+W blur on the INPUT (contiguous cold slab reads). in -> ws
//   2: D-blur slab; reads ws d-strided but L3-HOT; strided writes. ws -> out

#define WSZ 13
#define RAD 6

constexpr int BB = 4, DD = 160, HH = 160, WW = 160;
constexpr int R2 = 160;             // row in float2 (w extent)
constexpr int P2 = HH * WW;         // plane in float2 (25,600)
constexpr int N2 = DD * P2;         // batch in float2
constexpr int R4 = 80;              // row in float4
constexpr int P4 = P2 / 2;          // plane in float4 (12,800)
constexpr int N4 = N2 / 2;

// Pass 2 (D) tile
#define TBA 8                        // output d-rows per block
#define SLABRA (TBA + 12)            // 20 slab rows -> 25,600 B LDS
#define NTILEA (DD / TBA)            // 20 tiles

// Pass 1 (H+W) tile
#define TB 20
#define SLABR (TB + 12)              // 32 slab rows -> 40,960 B LDS
#define HBS 172                      // hbuf row stride

__device__ __forceinline__ void make_weights(float sig, float* w) {
    const float invd = 1.0f / (2.0f * sig * sig + 1e-7f);
    float s = 0.0f;
#pragma unroll
    for (int k = 0; k < WSZ; ++k) {
        const float loc = (float)(k - RAD);
        w[k] = __expf(-loc * loc * invd);
        s += w[k];
    }
    const float inv = 1.0f / s;
#pragma unroll
    for (int k = 0; k < WSZ; ++k) w[k] *= inv;
}

// ---------------- Pass 1: fused H+W blur, one (b,d,h-tile) per block ----------------
__global__ __launch_bounds__(320) void blur_hw(const float2* __restrict__ in,
                                               float2* __restrict__ ws,
                                               const float* __restrict__ sigma) {
    __shared__ __align__(16) float2 lds[SLABR * R2];   // 40,960 B

    const int tid  = threadIdx.x;
    const int bx   = blockIdx.x;
    const int tile = bx & 7;                 // 8 h-tiles of 20 rows
    const int d    = (bx >> 3) % DD;
    const int b    = bx / (8 * DD);
    const int h0   = tile * TB;

    float wh[WSZ];
    make_weights(sigma[b * 3 + 1], wh);

    const float2* plane = in + b * N2 + d * P2;

    // ---- load slab rows h0-6 .. h0+25 (32 x 160 f2) as float4: 8/thread ----
    const float4* p4 = (const float4*)plane;
    float4* l4 = (float4*)lds;
#pragma unroll
    for (int j = 0; j < 8; ++j) {
        const int f = j * 320 + tid;
        const int r = f / R4, q = f % R4;
        const int hh = h0 - 6 + r;
        float4 v = make_float4(0.f, 0.f, 0.f, 0.f);
        if (hh >= 0 && hh < HH) v = p4[hh * R4 + q];
        l4[f] = v;
    }
    __syncthreads();

    // ---- H-blur: one column-walk per thread ----
    float2 o[10];
    {
        const int w  = tid % 160;
        const int r0 = (tid / 160) * 10;
        float2 win[WSZ];
#pragma unroll
        for (int k = 0; k < WSZ - 1; ++k) win[k] = lds[(r0 + k) * R2 + w];
#pragma unroll
        for (int i = 0; i < 10; ++i) {
            win[WSZ - 1] = lds[(r0 + i + WSZ - 1) * R2 + w];
            float ax = 0.0f, ay = 0.0f;
#pragma unroll
            for (int k = 0; k < WSZ; ++k) { ax += wh[k] * win[k].x; ay += wh[k] * win[k].y; }
            o[i] = make_float2(ax, ay);
#pragma unroll
            for (int k = 0; k < WSZ - 1; ++k) win[k] = win[k + 1];
        }
    }
    __syncthreads();   // all slab reads done; reuse LDS as hbuf[20][172]

    // ---- write hbuf: zero stripes + data shifted +6 ----
    float2* hb = lds;
    if (tid < 240) {
        const int r = tid / 12, c = tid % 12;
        const int col = (c < 6) ? c : (160 + c);
        hb[r * HBS + col] = make_float2(0.0f, 0.0f);
    }
    {
        const int w  = tid % 160;
        const int r0 = (tid / 160) * 10;
#pragma unroll
        for (int i = 0; i < 10; ++i) hb[(r0 + i) * HBS + 6 + w] = o[i];
    }
    __syncthreads();

    // ---- W-blur: 3200 outputs, coalesced stores ----
    float ww[WSZ];
    make_weights(sigma[b * 3 + 2], ww);

    float2* oplane = ws + b * N2 + d * P2 + h0 * R2;
#pragma unroll
    for (int j = 0; j < 10; ++j) {
        const int oidx = j * 320 + tid;
        const int r = oidx / 160, w = oidx % 160;
        const float2* src = &hb[r * HBS + w];
        float ax = 0.0f, ay = 0.0f;
#pragma unroll
        for (int k = 0; k < WSZ; ++k) { const float2 v = src[k]; ax += ww[k] * v.x; ay += ww[k] * v.y; }
        oplane[oidx] = make_float2(ax, ay);
    }
}

// ---------------- Pass 2: D-blur, small LDS slab at fixed (b,h); ws is L3-hot ----------------
__global__ __launch_bounds__(320) void blur_d_slab(const float2* __restrict__ ws,
                                                   float2* __restrict__ out,
                                                   const float* __restrict__ sigma) {
    __shared__ __align__(16) float2 lds[SLABRA * R2];   // 25,600 B

    const int tid  = threadIdx.x;
    const int bx   = blockIdx.x;
    const int h    = bx % HH;                 // fastest
    const int tile = (bx / HH) % NTILEA;
    const int b    = bx / (NTILEA * HH);
    const int d0   = tile * TBA;

    float wd[WSZ];
    make_weights(sigma[b * 3 + 0], wd);

    // ---- stage slab rows d0-6 .. d0+13 (20 x 160 f2) as float4: 5/thread ----
    const float4* ws4 = (const float4*)ws;
    float4* l4 = (float4*)lds;
#pragma unroll
    for (int j = 0; j < 5; ++j) {
        const int f = j * 320 + tid;                    // 0..1599
        const int r = f / R4, q = f % R4;
        const int d = d0 - 6 + r;
        float4 v = make_float4(0.f, 0.f, 0.f, 0.f);
        if (d >= 0 && d < DD) v = ws4[b * N4 + d * P4 + h * R4 + q];
        l4[f] = v;
    }
    __syncthreads();

    // ---- column walk along d (4 outputs/thread); store d-strided (writes don't care) ----
    const int w  = tid % 160;
    const int r0 = (tid / 160) * 4;                     // 0 or 4
    float2* ocol = out + b * N2 + h * R2 + w;

    float2 win[WSZ];
#pragma unroll
    for (int k = 0; k < WSZ - 1; ++k) win[k] = lds[(r0 + k) * R2 + w];
#pragma unroll
    for (int i = 0; i < 4; ++i) {
        win[WSZ - 1] = lds[(r0 + i + WSZ - 1) * R2 + w];
        float ax = 0.0f, ay = 0.0f;
#pragma unroll
        for (int k = 0; k < WSZ; ++k) { ax += wd[k] * win[k].x; ay += wd[k] * win[k].y; }
        ocol[(d0 + r0 + i) * P2] = make_float2(ax, ay);
#pragma unroll
        for (int k = 0; k < WSZ - 1; ++k) win[k] = win[k + 1];
    }
}

extern "C" void kernel_launch(void* const* d_in, const int* in_sizes, int n_in,
                              void* d_out, int out_size, void* d_ws, size_t ws_size,
                              hipStream_t stream) {
    const float2* img   = (const float2*)d_in[0];
    const float*  sigma = (const float*)d_in[1];
    float2* out = (float2*)d_out;
    float2* ws  = (float2*)d_ws;

    blur_hw<<<dim3(BB * DD * 8), dim3(320), 0, stream>>>(img, ws, sigma);
    blur_d_slab<<<dim3(BB * NTILEA * HH), dim3(320), 0, stream>>>(ws, out, sigma);
}

// Round 10
// 128.495 us; speedup vs baseline: 1.0021x; 1.0021x over previous
//
#include <hip/hip_runtime.h>

// DynamicGaussianBlur: [B=4, D=160, H=160, W=160, C=2] fp32, sigma [4,3],
// separable 3D gaussian, window 13 (radius 6), SAME zero padding.
// Two passes, channel-interleaved float2:
//   A: D-blur, software-pipelined d-walker (double-buffered LDS slab,
//      prefetch tile t+2 regs while computing tile t). COLD reads stay
//      continuously in flight.                              in -> ws
//   B: fused H+W blur per (b,d,h-tile), reads L3-hot ws.    ws -> out

#define WSZ 13
#define RAD 6

constexpr int BB = 4, DD = 160, HH = 160, WW = 160;
constexpr int R2 = 160;             // row in float2 (w extent)
constexpr int P2 = HH * WW;         // plane in float2 (25,600)
constexpr int N2 = DD * P2;         // batch in float2
constexpr int R4 = 80;              // row in float4
constexpr int P4 = P2 / 2;          // plane in float4 (12,800)
constexpr int N4 = N2 / 2;

// Pass A: d-walker
#define TD 8                         // output d-rows per tile
#define SLABD (TD + 12)              // 20 slab rows per buffer (25,600 B)
#define NT 10                        // tiles per block (d-half of 80)

// Pass B tile
#define TB 20
#define SLABR (TB + 12)              // 32 slab rows -> 40,960 B LDS
#define HBS 172                      // hbuf row stride

__device__ __forceinline__ void make_weights(float sig, float* w) {
    const float invd = 1.0f / (2.0f * sig * sig + 1e-7f);
    float s = 0.0f;
#pragma unroll
    for (int k = 0; k < WSZ; ++k) {
        const float loc = (float)(k - RAD);
        w[k] = __expf(-loc * loc * invd);
        s += w[k];
    }
    const float inv = 1.0f / s;
#pragma unroll
    for (int k = 0; k < WSZ; ++k) w[k] *= inv;
}

// ---------------- Pass A: pipelined D-blur walker ----------------
__global__ __launch_bounds__(320) void blur_d_pipe(const float2* __restrict__ in,
                                                   float2* __restrict__ ws,
                                                   const float* __restrict__ sigma) {
    __shared__ __align__(16) float2 buf[2][SLABD * R2];   // 2 x 25,600 B

    const int tid  = threadIdx.x;
    const int bx   = blockIdx.x;
    const int h    = bx % HH;                 // fastest: co-running blocks stream rows
    const int half = (bx / HH) & 1;
    const int b    = bx / (2 * HH);
    const int dstart = half * 80;

    float wd[WSZ];
    make_weights(sigma[b * 3 + 0], wd);

    const float4* in4  = (const float4*)in;
    const int     base4 = b * N4 + h * R4;

    const int w  = tid % 160;
    const int r0 = (tid / 160) * 4;           // 0 or 4 (2 segments of 4 outputs)
    float2* ocol = ws + b * N2 + h * R2 + w;

    float4 pre[5];

#define STAGE(T) do {                                                   \
    const int rlo = dstart + (T) * TD - 6;                              \
    _Pragma("unroll")                                                   \
    for (int j = 0; j < 5; ++j) {                                       \
        const int f = j * 320 + tid;                                    \
        const int r = f / R4, q = f % R4;                               \
        const int d = rlo + r;                                          \
        float4 v = make_float4(0.f, 0.f, 0.f, 0.f);                     \
        if (d >= 0 && d < DD) v = in4[base4 + d * P4 + q];              \
        pre[j] = v;                                                     \
    } } while (0)

#define WRITEB(C) do {                                                  \
    float4* dst4 = (float4*)buf[C];                                     \
    _Pragma("unroll")                                                   \
    for (int j = 0; j < 5; ++j) dst4[j * 320 + tid] = pre[j];           \
    } while (0)

    // prologue: tile 0 staged and visible; tile 1 loads in flight
    STAGE(0); WRITEB(0); __syncthreads();
    STAGE(1);

    int cur = 0;
    for (int t = 0; t < NT; ++t) {
        // 1) retire in-flight loads (tile t+1) into the other buffer
        if (t + 1 < NT) WRITEB(cur ^ 1);
        // 2) issue tile t+2 loads — in flight across the whole compute below
        if (t + 2 < NT) STAGE(t + 2);
        // 3) compute tile t from buf[cur]
        {
            const float2* bp = buf[cur];
            const int d0 = dstart + t * TD;
            float2 win[WSZ];
#pragma unroll
            for (int k = 0; k < 12; ++k) win[k] = bp[(r0 + k) * R2 + w];
#pragma unroll
            for (int i = 0; i < 4; ++i) {
                win[12] = bp[(r0 + i + 12) * R2 + w];
                float ax = 0.0f, ay = 0.0f;
#pragma unroll
                for (int k = 0; k < WSZ; ++k) { ax += wd[k] * win[k].x; ay += wd[k] * win[k].y; }
                ocol[(d0 + r0 + i) * P2] = make_float2(ax, ay);
#pragma unroll
                for (int k = 0; k < 12; ++k) win[k] = win[k + 1];
            }
        }
        // 4) make next buffer visible
        if (t + 1 < NT) { __syncthreads(); cur ^= 1; }
    }
#undef STAGE
#undef WRITEB
}

// ---------------- Pass B: fused H+W blur, one (b,d,h-tile) per block (hot ws) ----------------
__global__ __launch_bounds__(320) void blur_hw(const float2* __restrict__ ws,
                                               float2* __restrict__ out,
                                               const float* __restrict__ sigma) {
    __shared__ __align__(16) float2 lds[SLABR * R2];   // 40,960 B

    const int tid  = threadIdx.x;
    const int bx   = blockIdx.x;
    const int tile = bx & 7;                 // 8 h-tiles of 20 rows
    const int d    = (bx >> 3) % DD;
    const int b    = bx / (8 * DD);
    const int h0   = tile * TB;

    float wh[WSZ];
    make_weights(sigma[b * 3 + 1], wh);

    const float2* plane = ws + b * N2 + d * P2;

    // ---- load slab rows h0-6 .. h0+25 (32 x 160 f2) as float4: 8/thread ----
    const float4* p4 = (const float4*)plane;
    float4* l4 = (float4*)lds;
#pragma unroll
    for (int j = 0; j < 8; ++j) {
        const int f = j * 320 + tid;
        const int r = f / R4, q = f % R4;
        const int hh = h0 - 6 + r;
        float4 v = make_float4(0.f, 0.f, 0.f, 0.f);
        if (hh >= 0 && hh < HH) v = p4[hh * R4 + q];
        l4[f] = v;
    }
    __syncthreads();

    // ---- H-blur: one column-walk per thread ----
    float2 o[10];
    {
        const int w  = tid % 160;
        const int r0 = (tid / 160) * 10;
        float2 win[WSZ];
#pragma unroll
        for (int k = 0; k < WSZ - 1; ++k) win[k] = lds[(r0 + k) * R2 + w];
#pragma unroll
        for (int i = 0; i < 10; ++i) {
            win[WSZ - 1] = lds[(r0 + i + WSZ - 1) * R2 + w];
            float ax = 0.0f, ay = 0.0f;
#pragma unroll
            for (int k = 0; k < WSZ; ++k) { ax += wh[k] * win[k].x; ay += wh[k] * win[k].y; }
            o[i] = make_float2(ax, ay);
#pragma unroll
            for (int k = 0; k < WSZ - 1; ++k) win[k] = win[k + 1];
        }
    }
    __syncthreads();   // all slab reads done; reuse LDS as hbuf[20][172]

    // ---- write hbuf: zero stripes + data shifted +6 ----
    float2* hb = lds;
    if (tid < 240) {
        const int r = tid / 12, c = tid % 12;
        const int col = (c < 6) ? c : (160 + c);
        hb[r * HBS + col] = make_float2(0.0f, 0.0f);
    }
    {
        const int w  = tid % 160;
        const int r0 = (tid / 160) * 10;
#pragma unroll
        for (int i = 0; i < 10; ++i) hb[(r0 + i) * HBS + 6 + w] = o[i];
    }
    __syncthreads();

    // ---- W-blur: 3200 outputs, coalesced stores ----
    float ww[WSZ];
    make_weights(sigma[b * 3 + 2], ww);

    float2* oplane = out + b * N2 + d * P2 + h0 * R2;
#pragma unroll
    for (int j = 0; j < 10; ++j) {
        const int oidx = j * 320 + tid;
        const int r = oidx / 160, w = oidx % 160;
        const float2* src = &hb[r * HBS + w];
        float ax = 0.0f, ay = 0.0f;
#pragma unroll
        for (int k = 0; k < WSZ; ++k) { const float2 v = src[k]; ax += ww[k] * v.x; ay += ww[k] * v.y; }
        oplane[oidx] = make_float2(ax, ay);
    }
}

extern "C" void kernel_launch(void* const* d_in, const int* in_sizes, int n_in,
                              void* d_out, int out_size, void* d_ws, size_t ws_size,
                              hipStream_t stream) {
    const float2* img   = (const float2*)d_in[0];
    const float*  sigma = (const float*)d_in[1];
    float2* out = (float2*)d_out;
    float2* ws  = (float2*)d_ws;

    blur_d_pipe<<<dim3(BB * 2 * HH), dim3(320), 0, stream>>>(img, ws, sigma);
    blur_hw<<<dim3(BB * DD * 8), dim3(320), 0, stream>>>(ws, out, sigma);
}

// Round 12
// 116.534 us; speedup vs baseline: 1.1050x; 1.1026x over previous
//
#include <hip/hip_runtime.h>

// DynamicGaussianBlur: [B=4, D=160, H=160, W=160, C=2] fp32, sigma [4,3],
// separable 3D gaussian, window 13 (radius 6), SAME zero padding.
// Two passes, channel-interleaved float2, L3-policy-aware:
//   A: D-blur register line-walk. INPUT loads are NONTEMPORAL (don't
//      allocate in L3 -> no dirty-line eviction storm); ws stores normal
//      (ws stays L3-resident for pass B).                     in -> ws
//   B: fused H+W blur per (b,d,h-tile); ws reads L3-hot; OUT stores
//      NONTEMPORAL (never re-read, don't evict ws).           ws -> out

#define WSZ 13
#define RAD 6
#define SEGA 40       // pass A: axis segment per thread
#define NSEGA 4

typedef float nfloat2 __attribute__((ext_vector_type(2)));   // nt-capable float2

constexpr int BB = 4, DD = 160, HH = 160, WW = 160;
constexpr int R2 = 160;             // row in float2
constexpr int P2 = HH * WW;         // plane in float2 (25,600)
constexpr int N2 = DD * P2;         // batch in float2
constexpr int R4 = 80;              // row in float4
constexpr int NCOL = BB * P2;       // pass-A columns (102,400)

// Pass B tile
#define TB 20
#define SLABR (TB + 12)              // 32 slab rows -> 40,960 B LDS
#define HBS 172                      // hbuf row stride

__device__ __forceinline__ void make_weights(float sig, float* w) {
    const float invd = 1.0f / (2.0f * sig * sig + 1e-7f);
    float s = 0.0f;
#pragma unroll
    for (int k = 0; k < WSZ; ++k) {
        const float loc = (float)(k - RAD);
        w[k] = __expf(-loc * loc * invd);
        s += w[k];
    }
    const float inv = 1.0f / s;
#pragma unroll
    for (int k = 0; k < WSZ; ++k) w[k] *= inv;
}

// ---------------- Pass A: D-blur register walk, nontemporal input reads ----------------
__global__ __launch_bounds__(256) void blur_d(const float2* __restrict__ in,
                                              float2* __restrict__ ws,
                                              const float* __restrict__ sigma) {
    const nfloat2* inN = (const nfloat2*)in;

    const int cid = blockIdx.x * 256 + threadIdx.x;
    const int b   = cid / P2;                        // uniform per block
    const int rem = cid % P2;
    const int h   = rem / 160;
    const int w2  = rem % 160;

    float wgt[WSZ];
    make_weights(sigma[b * 3 + 0], wgt);

    const int base2 = b * N2 + h * R2 + w2;
    const int p0 = blockIdx.y * SEGA;

    float wx[WSZ], wy[WSZ];
#pragma unroll
    for (int k = 0; k < WSZ; ++k) {
        const int q = p0 - RAD + k;
        nfloat2 v = (nfloat2)(0.0f);
        if (q >= 0 && q < DD) v = __builtin_nontemporal_load(&inN[base2 + q * P2]);
        wx[k] = v.x; wy[k] = v.y;
    }

#pragma unroll 4
    for (int i = 0; i < SEGA; ++i) {
        float ax = 0.0f, ay = 0.0f;
#pragma unroll
        for (int k = 0; k < WSZ; ++k) { ax += wgt[k] * wx[k]; ay += wgt[k] * wy[k]; }
        ws[base2 + (p0 + i) * P2] = make_float2(ax, ay);   // normal store: keep in L3

#pragma unroll
        for (int k = 0; k < WSZ - 1; ++k) { wx[k] = wx[k + 1]; wy[k] = wy[k + 1]; }
        const int q = p0 + i + RAD + 1;
        nfloat2 v = (nfloat2)(0.0f);
        if (q < DD) v = __builtin_nontemporal_load(&inN[base2 + q * P2]);
        wx[WSZ - 1] = v.x; wy[WSZ - 1] = v.y;
    }
}

// ---------------- Pass B: fused H+W blur, one (b,d,h-tile) per block ----------------
__global__ __launch_bounds__(320) void blur_hw(const float2* __restrict__ ws,
                                               float2* __restrict__ out,
                                               const float* __restrict__ sigma) {
    __shared__ __align__(16) float2 lds[SLABR * R2];   // 40,960 B

    const int tid  = threadIdx.x;
    const int bx   = blockIdx.x;
    const int tile = bx & 7;                 // 8 h-tiles of 20 rows
    const int d    = (bx >> 3) % DD;
    const int b    = bx / (8 * DD);
    const int h0   = tile * TB;

    float wh[WSZ];
    make_weights(sigma[b * 3 + 1], wh);

    const float2* plane = ws + b * N2 + d * P2;

    // ---- load slab rows h0-6 .. h0+25 (32 x 160 f2) as float4: 8/thread ----
    const float4* p4 = (const float4*)plane;
    float4* l4 = (float4*)lds;
#pragma unroll
    for (int j = 0; j < 8; ++j) {
        const int f = j * 320 + tid;
        const int r = f / R4, q = f % R4;
        const int hh = h0 - 6 + r;
        float4 v = make_float4(0.f, 0.f, 0.f, 0.f);
        if (hh >= 0 && hh < HH) v = p4[hh * R4 + q];
        l4[f] = v;
    }
    __syncthreads();

    // ---- H-blur: one column-walk per thread ----
    float2 o[10];
    {
        const int w  = tid % 160;
        const int r0 = (tid / 160) * 10;
        float2 win[WSZ];
#pragma unroll
        for (int k = 0; k < WSZ - 1; ++k) win[k] = lds[(r0 + k) * R2 + w];
#pragma unroll
        for (int i = 0; i < 10; ++i) {
            win[WSZ - 1] = lds[(r0 + i + WSZ - 1) * R2 + w];
            float ax = 0.0f, ay = 0.0f;
#pragma unroll
            for (int k = 0; k < WSZ; ++k) { ax += wh[k] * win[k].x; ay += wh[k] * win[k].y; }
            o[i] = make_float2(ax, ay);
#pragma unroll
            for (int k = 0; k < WSZ - 1; ++k) win[k] = win[k + 1];
        }
    }
    __syncthreads();   // all slab reads done; reuse LDS as hbuf[20][172]

    // ---- write hbuf: zero stripes + data shifted +6 ----
    float2* hb = lds;
    if (tid < 240) {
        const int r = tid / 12, c = tid % 12;
        const int col = (c < 6) ? c : (160 + c);
        hb[r * HBS + col] = make_float2(0.0f, 0.0f);
    }
    {
        const int w  = tid % 160;
        const int r0 = (tid / 160) * 10;
#pragma unroll
        for (int i = 0; i < 10; ++i) hb[(r0 + i) * HBS + 6 + w] = o[i];
    }
    __syncthreads();

    // ---- W-blur: 3200 outputs, coalesced NONTEMPORAL stores ----
    float ww[WSZ];
    make_weights(sigma[b * 3 + 2], ww);

    nfloat2* oplane = (nfloat2*)(out + b * N2 + d * P2 + h0 * R2);
#pragma unroll
    for (int j = 0; j < 10; ++j) {
        const int oidx = j * 320 + tid;
        const int r = oidx / 160, w = oidx % 160;
        const float2* src = &hb[r * HBS + w];
        float ax = 0.0f, ay = 0.0f;
#pragma unroll
        for (int k = 0; k < WSZ; ++k) { const float2 v = src[k]; ax += ww[k] * v.x; ay += ww[k] * v.y; }
        nfloat2 res; res.x = ax; res.y = ay;
        __builtin_nontemporal_store(res, &oplane[oidx]);
    }
}

extern "C" void kernel_launch(void* const* d_in, const int* in_sizes, int n_in,
                              void* d_out, int out_size, void* d_ws, size_t ws_size,
                              hipStream_t stream) {
    const float2* img   = (const float2*)d_in[0];
    const float*  sigma = (const float*)d_in[1];
    float2* out = (float2*)d_out;
    float2* ws  = (float2*)d_ws;

    blur_d<<<dim3(NCOL / 256, NSEGA), dim3(256), 0, stream>>>(img, ws, sigma);
    blur_hw<<<dim3(BB * DD * 8), dim3(320), 0, stream>>>(ws, out, sigma);
}

// Round 13
// 96.785 us; speedup vs baseline: 1.3304x; 1.2041x over previous
//
#include <hip/hip_runtime.h>
#include <hip/hip_fp16.h>

// DynamicGaussianBlur: [B=4, D=160, H=160, W=160, C=2] fp32, sigma [4,3],
// separable 3D gaussian, window 13 (radius 6), SAME zero padding.
// Two passes; ws is FP16 (half2 = channel pair) to halve intermediate
// traffic and let {input + ws} fit in the 256 MB L3 across graph replays:
//   A: D-blur register line-walk, normal (caching) input loads. in -> ws(fp16)
//   B: fused H+W blur per (b,d,h-tile); ws reads L3-hot; OUT stores
//      nontemporal (never re-read, don't evict in/ws).        ws -> out

#define WSZ 13
#define RAD 6
#define SEGA 40       // pass A: axis segment per thread
#define NSEGA 4

typedef float nfloat2 __attribute__((ext_vector_type(2)));   // nt-capable float2

constexpr int BB = 4, DD = 160, HH = 160, WW = 160;
constexpr int R2 = 160;             // row in float2 / half2 units
constexpr int P2 = HH * WW;         // plane (25,600)
constexpr int N2 = DD * P2;         // batch volume
constexpr int NCOL = BB * P2;       // pass-A columns (102,400)

// Pass B tile
#define TB 20
#define SLABR (TB + 12)              // 32 slab rows -> 40,960 B LDS
#define HBS 172                      // hbuf row stride

__device__ __forceinline__ void make_weights(float sig, float* w) {
    const float invd = 1.0f / (2.0f * sig * sig + 1e-7f);
    float s = 0.0f;
#pragma unroll
    for (int k = 0; k < WSZ; ++k) {
        const float loc = (float)(k - RAD);
        w[k] = __expf(-loc * loc * invd);
        s += w[k];
    }
    const float inv = 1.0f / s;
#pragma unroll
    for (int k = 0; k < WSZ; ++k) w[k] *= inv;
}

// ---------------- Pass A: D-blur register walk, fp16 ws output ----------------
__global__ __launch_bounds__(256) void blur_d(const float2* __restrict__ in,
                                              __half2* __restrict__ ws,
                                              const float* __restrict__ sigma) {
    const int cid = blockIdx.x * 256 + threadIdx.x;
    const int b   = cid / P2;                        // uniform per block
    const int rem = cid % P2;
    const int h   = rem / 160;
    const int w2  = rem % 160;

    float wgt[WSZ];
    make_weights(sigma[b * 3 + 0], wgt);

    const int base2 = b * N2 + h * R2 + w2;
    const int p0 = blockIdx.y * SEGA;

    float wx[WSZ], wy[WSZ];
#pragma unroll
    for (int k = 0; k < WSZ; ++k) {
        const int q = p0 - RAD + k;
        float2 v = make_float2(0.0f, 0.0f);
        if (q >= 0 && q < DD) v = in[base2 + q * P2];   // normal load: keep in L3
        wx[k] = v.x; wy[k] = v.y;
    }

#pragma unroll 4
    for (int i = 0; i < SEGA; ++i) {
        float ax = 0.0f, ay = 0.0f;
#pragma unroll
        for (int k = 0; k < WSZ; ++k) { ax += wgt[k] * wx[k]; ay += wgt[k] * wy[k]; }
        ws[base2 + (p0 + i) * P2] = __float22half2_rn(make_float2(ax, ay));

#pragma unroll
        for (int k = 0; k < WSZ - 1; ++k) { wx[k] = wx[k + 1]; wy[k] = wy[k + 1]; }
        const int q = p0 + i + RAD + 1;
        float2 v = make_float2(0.0f, 0.0f);
        if (q < DD) v = in[base2 + q * P2];
        wx[WSZ - 1] = v.x; wy[WSZ - 1] = v.y;
    }
}

// ---------------- Pass B: fused H+W blur, one (b,d,h-tile) per block ----------------
__global__ __launch_bounds__(320) void blur_hw(const __half2* __restrict__ ws,
                                               float2* __restrict__ out,
                                               const float* __restrict__ sigma) {
    __shared__ __align__(16) float2 lds[SLABR * R2];   // 40,960 B

    const int tid  = threadIdx.x;
    const int bx   = blockIdx.x;
    const int tile = bx & 7;                 // 8 h-tiles of 20 rows
    const int d    = (bx >> 3) % DD;
    const int b    = bx / (8 * DD);
    const int h0   = tile * TB;

    float wh[WSZ];
    make_weights(sigma[b * 3 + 1], wh);

    // ---- load slab rows h0-6 .. h0+25 (32 x 160 half2), convert to f32 LDS ----
    // fp16 row = 160 half2 = 640 B = 40 float4; slab = 32 x 40 = 1280 float4
    const float4* p4 = (const float4*)(ws + b * N2 + d * P2);
#pragma unroll
    for (int j = 0; j < 4; ++j) {
        const int f = j * 320 + tid;                   // 0..1279
        const int r = f / 40, q = f % 40;
        const int hh = h0 - 6 + r;
        union { float4 f4; __half2 h2[4]; } u;
        u.f4 = make_float4(0.f, 0.f, 0.f, 0.f);
        if (hh >= 0 && hh < HH) u.f4 = p4[hh * 40 + q];
#pragma unroll
        for (int t = 0; t < 4; ++t) lds[r * R2 + q * 4 + t] = __half22float2(u.h2[t]);
    }
    __syncthreads();

    // ---- H-blur: one column-walk per thread ----
    float2 o[10];
    {
        const int w  = tid % 160;
        const int r0 = (tid / 160) * 10;
        float2 win[WSZ];
#pragma unroll
        for (int k = 0; k < WSZ - 1; ++k) win[k] = lds[(r0 + k) * R2 + w];
#pragma unroll
        for (int i = 0; i < 10; ++i) {
            win[WSZ - 1] = lds[(r0 + i + WSZ - 1) * R2 + w];
            float ax = 0.0f, ay = 0.0f;
#pragma unroll
            for (int k = 0; k < WSZ; ++k) { ax += wh[k] * win[k].x; ay += wh[k] * win[k].y; }
            o[i] = make_float2(ax, ay);
#pragma unroll
            for (int k = 0; k < WSZ - 1; ++k) win[k] = win[k + 1];
        }
    }
    __syncthreads();   // all slab reads done; reuse LDS as hbuf[20][172]

    // ---- write hbuf: zero stripes + data shifted +6 ----
    float2* hb = lds;
    if (tid < 240) {
        const int r = tid / 12, c = tid % 12;
        const int col = (c < 6) ? c : (160 + c);
        hb[r * HBS + col] = make_float2(0.0f, 0.0f);
    }
    {
        const int w  = tid % 160;
        const int r0 = (tid / 160) * 10;
#pragma unroll
        for (int i = 0; i < 10; ++i) hb[(r0 + i) * HBS + 6 + w] = o[i];
    }
    __syncthreads();

    // ---- W-blur: 3200 outputs, coalesced NONTEMPORAL stores ----
    float ww[WSZ];
    make_weights(sigma[b * 3 + 2], ww);

    nfloat2* oplane = (nfloat2*)(out + b * N2 + d * P2 + h0 * R2);
#pragma unroll
    for (int j = 0; j < 10; ++j) {
        const int oidx = j * 320 + tid;
        const int r = oidx / 160, w = oidx % 160;
        const float2* src = &hb[r * HBS + w];
        float ax = 0.0f, ay = 0.0f;
#pragma unroll
        for (int k = 0; k < WSZ; ++k) { const float2 v = src[k]; ax += ww[k] * v.x; ay += ww[k] * v.y; }
        nfloat2 res; res.x = ax; res.y = ay;
        __builtin_nontemporal_store(res, &oplane[oidx]);
    }
}

extern "C" void kernel_launch(void* const* d_in, const int* in_sizes, int n_in,
                              void* d_out, int out_size, void* d_ws, size_t ws_size,
                              hipStream_t stream) {
    const float2* img   = (const float2*)d_in[0];
    const float*  sigma = (const float*)d_in[1];
    float2*  out = (float2*)d_out;
    __half2* ws  = (__half2*)d_ws;

    blur_d<<<dim3(NCOL / 256, NSEGA), dim3(256), 0, stream>>>(img, ws, sigma);
    blur_hw<<<dim3(BB * DD * 8), dim3(320), 0, stream>>>(ws, out, sigma);
}

// Round 14
// 90.103 us; speedup vs baseline: 1.4291x; 1.0742x over previous
//
#include <hip/hip_runtime.h>
#include <hip/hip_fp16.h>

// DynamicGaussianBlur: [B=4, D=160, H=160, W=160, C=2] fp32, sigma [4,3],
// separable 3D gaussian, window 13 (radius 6), SAME zero padding.
// Two passes; ws is FP16 (half2 = channel pair):
//   A: D-blur register line-walk, float4-wide (2 f2 columns per thread,
//      16B loads, 8B packed half2x2 stores).               in -> ws(fp16)
//   B: fused H+W blur per (b,d,h-tile); ws reads L3-hot; OUT stores
//      nontemporal (never re-read, don't evict in/ws).     ws -> out

#define WSZ 13
#define RAD 6
#define SEGA 40       // pass A: d-segment per thread
#define NSEGA 4

typedef float nfloat2 __attribute__((ext_vector_type(2)));   // nt-capable float2

constexpr int BB = 4, DD = 160, HH = 160, WW = 160;
constexpr int R2 = 160;             // row in float2 / half2 units
constexpr int P2 = HH * WW;         // plane (25,600)
constexpr int N2 = DD * P2;         // batch volume
constexpr int P4 = P2 / 2;          // plane in float4 / uint2 units (12,800)
constexpr int N4 = N2 / 2;
constexpr int NCOL4 = BB * P4;      // pass-A float4 columns (51,200)

// Pass B tile
#define TB 20
#define SLABR (TB + 12)              // 32 slab rows -> 40,960 B LDS
#define HBS 172                      // hbuf row stride

__device__ __forceinline__ void make_weights(float sig, float* w) {
    const float invd = 1.0f / (2.0f * sig * sig + 1e-7f);
    float s = 0.0f;
#pragma unroll
    for (int k = 0; k < WSZ; ++k) {
        const float loc = (float)(k - RAD);
        w[k] = __expf(-loc * loc * invd);
        s += w[k];
    }
    const float inv = 1.0f / s;
#pragma unroll
    for (int k = 0; k < WSZ; ++k) w[k] *= inv;
}

// ---------------- Pass A: D-blur register walk, float4-wide, fp16 ws ----------------
__global__ __launch_bounds__(256) void blur_d(const float2* __restrict__ in,
                                              __half2* __restrict__ ws,
                                              const float* __restrict__ sigma) {
    const float4* in4 = (const float4*)in;
    uint2* wsU = (uint2*)ws;

    const int cid = blockIdx.x * 256 + threadIdx.x;   // float4-column id
    const int b   = cid / P4;                         // uniform per block
    const int rem = cid % P4;                         // position within plane (f4 units)

    float wgt[WSZ];
    make_weights(sigma[b * 3 + 0], wgt);

    const int ibase = b * N4 + rem;                   // float4 index at d=0
    const int obase = b * (N2 / 2) + rem;             // uint2 index at d=0
    const int p0 = blockIdx.y * SEGA;

    float4 win[WSZ];
#pragma unroll
    for (int k = 0; k < WSZ; ++k) {
        const int q = p0 - RAD + k;
        float4 v = make_float4(0.f, 0.f, 0.f, 0.f);
        if (q >= 0 && q < DD) v = in4[ibase + q * P4];
        win[k] = v;
    }

#pragma unroll 4
    for (int i = 0; i < SEGA; ++i) {
        float ax0 = 0.f, ay0 = 0.f, ax1 = 0.f, ay1 = 0.f;
#pragma unroll
        for (int k = 0; k < WSZ; ++k) {
            const float4 v = win[k];
            ax0 += wgt[k] * v.x; ay0 += wgt[k] * v.y;
            ax1 += wgt[k] * v.z; ay1 += wgt[k] * v.w;
        }
        union { uint2 u; __half2 h[2]; } o;
        o.h[0] = __float22half2_rn(make_float2(ax0, ay0));
        o.h[1] = __float22half2_rn(make_float2(ax1, ay1));
        wsU[obase + (p0 + i) * P4] = o.u;             // normal store: keep ws in L3

#pragma unroll
        for (int k = 0; k < WSZ - 1; ++k) win[k] = win[k + 1];
        const int q = p0 + i + RAD + 1;
        float4 v = make_float4(0.f, 0.f, 0.f, 0.f);
        if (q < DD) v = in4[ibase + q * P4];
        win[WSZ - 1] = v;
    }
}

// ---------------- Pass B: fused H+W blur, one (b,d,h-tile) per block ----------------
__global__ __launch_bounds__(320) void blur_hw(const __half2* __restrict__ ws,
                                               float2* __restrict__ out,
                                               const float* __restrict__ sigma) {
    __shared__ __align__(16) float2 lds[SLABR * R2];   // 40,960 B

    const int tid  = threadIdx.x;
    const int bx   = blockIdx.x;
    const int tile = bx & 7;                 // 8 h-tiles of 20 rows
    const int d    = (bx >> 3) % DD;
    const int b    = bx / (8 * DD);
    const int h0   = tile * TB;

    float wh[WSZ];
    make_weights(sigma[b * 3 + 1], wh);

    // ---- load slab rows h0-6 .. h0+25 (32 x 160 half2), convert to f32 LDS ----
    const float4* p4 = (const float4*)(ws + b * N2 + d * P2);   // 40 f4 per fp16 row
#pragma unroll
    for (int j = 0; j < 4; ++j) {
        const int f = j * 320 + tid;                   // 0..1279
        const int r = f / 40, q = f % 40;
        const int hh = h0 - 6 + r;
        union { float4 f4; __half2 h2[4]; } u;
        u.f4 = make_float4(0.f, 0.f, 0.f, 0.f);
        if (hh >= 0 && hh < HH) u.f4 = p4[hh * 40 + q];
#pragma unroll
        for (int t = 0; t < 4; ++t) lds[r * R2 + q * 4 + t] = __half22float2(u.h2[t]);
    }
    __syncthreads();

    // ---- H-blur: one column-walk per thread ----
    float2 o[10];
    {
        const int w  = tid % 160;
        const int r0 = (tid / 160) * 10;
        float2 win[WSZ];
#pragma unroll
        for (int k = 0; k < WSZ - 1; ++k) win[k] = lds[(r0 + k) * R2 + w];
#pragma unroll
        for (int i = 0; i < 10; ++i) {
            win[WSZ - 1] = lds[(r0 + i + WSZ - 1) * R2 + w];
            float ax = 0.0f, ay = 0.0f;
#pragma unroll
            for (int k = 0; k < WSZ; ++k) { ax += wh[k] * win[k].x; ay += wh[k] * win[k].y; }
            o[i] = make_float2(ax, ay);
#pragma unroll
            for (int k = 0; k < WSZ - 1; ++k) win[k] = win[k + 1];
        }
    }
    __syncthreads();   // all slab reads done; reuse LDS as hbuf[20][172]

    // ---- write hbuf: zero stripes + data shifted +6 ----
    float2* hb = lds;
    if (tid < 240) {
        const int r = tid / 12, c = tid % 12;
        const int col = (c < 6) ? c : (160 + c);
        hb[r * HBS + col] = make_float2(0.0f, 0.0f);
    }
    {
        const int w  = tid % 160;
        const int r0 = (tid / 160) * 10;
#pragma unroll
        for (int i = 0; i < 10; ++i) hb[(r0 + i) * HBS + 6 + w] = o[i];
    }
    __syncthreads();

    // ---- W-blur: 3200 outputs, coalesced NONTEMPORAL stores ----
    float ww[WSZ];
    make_weights(sigma[b * 3 + 2], ww);

    nfloat2* oplane = (nfloat2*)(out + b * N2 + d * P2 + h0 * R2);
#pragma unroll
    for (int j = 0; j < 10; ++j) {
        const int oidx = j * 320 + tid;
        const int r = oidx / 160, w = oidx % 160;
        const float2* src = &hb[r * HBS + w];
        float ax = 0.0f, ay = 0.0f;
#pragma unroll
        for (int k = 0; k < WSZ; ++k) { const float2 v = src[k]; ax += ww[k] * v.x; ay += ww[k] * v.y; }
        nfloat2 res; res.x = ax; res.y = ay;
        __builtin_nontemporal_store(res, &oplane[oidx]);
    }
}

extern "C" void kernel_launch(void* const* d_in, const int* in_sizes, int n_in,
                              void* d_out, int out_size, void* d_ws, size_t ws_size,
                              hipStream_t stream) {
    const float2* img   = (const float2*)d_in[0];
    const float*  sigma = (const float*)d_in[1];
    float2*  out = (float2*)d_out;
    __half2* ws  = (__half2*)d_ws;

    blur_d<<<dim3(NCOL4 / 256, NSEGA), dim3(256), 0, stream>>>(img, ws, sigma);
    blur_hw<<<dim3(BB * DD * 8), dim3(320), 0, stream>>>(ws, out, sigma);
}